// Round 8
// baseline (96.719 us; speedup 1.0000x reference)
//
#include <hip/hip_runtime.h>

#define NN   2048
#define IN   64
#define HID  32
#define OUTD 16

// 2 nodes, no barriers, no atomics, no memset.
// Node A (64 blocks): s0 partials + z = x@W1 tiles (linear part, no global dep),
//   z stored transposed for coalesced column access.
// Node B (16 blocks x 128 rows): s0 reduce -> agg1 -> redundant-but-cheap
//   s1 = colsum(relu(z+agg1)) (256 KB/block, 16 blocks = 4 MB total, staggered)
//   -> agg2 -> out.
//
// ws layout (floats), all write-before-read (0xAA poison harmless):
//   [S0P, S0P+64*64)   per-block partial colsums of x
//   [ZT,  ZT+32*2048)  z transposed: zT[h][row]
#define S0P 0
#define ZT  4096

// ---------------------------------------------------------------- node A ---
__global__ __launch_bounds__(256) void kA_z_s0(const float* __restrict__ x,
                                               const float* __restrict__ loop_w1,
                                               float* __restrict__ ws) {
    __shared__ float xsh[32 * IN];     // 8 KB own x tile
    __shared__ float w1sh[IN * HID];   // 8 KB
    __shared__ float zsh[32 * 33];     // z tile, padded
    __shared__ float red[256];
    const int tid = threadIdx.x, b = blockIdx.x;   // 64 blocks x 32 rows

    const float4* xt4 = (const float4*)(x + b * 32 * IN);
    const float4* w14 = (const float4*)loop_w1;
    float4 xa = xt4[tid], xb = xt4[tid + 256];
    float4 wa = w14[tid], wb = w14[tid + 256];
    ((float4*)xsh)[tid] = xa;  ((float4*)xsh)[tid + 256] = xb;
    ((float4*)w1sh)[tid] = wa; ((float4*)w1sh)[tid + 256] = wb;
    __syncthreads();

    // s0 partial colsum of own 32 rows
    {
        const int col = tid & 63, grp = tid >> 6;
        float s = 0.f;
#pragma unroll
        for (int r = 0; r < 8; ++r) s += xsh[(grp * 8 + r) * IN + col];
        red[tid] = s;
    }
    __syncthreads();
    if (tid < 64)
        ws[S0P + b * 64 + tid] = red[tid] + red[tid + 64] + red[tid + 128] + red[tid + 192];

    // z = x @ W1 for own 32 rows (linear part only)
    {
        const int h = tid & 31, rgrp = tid >> 5;
        float a0 = 0.f, a1 = 0.f, a2 = 0.f, a3 = 0.f;
#pragma unroll
        for (int k = 0; k < IN; ++k) {
            const float w = w1sh[k * HID + h];         // wave broadcast
            a0 += xsh[(rgrp +  0) * IN + k] * w;
            a1 += xsh[(rgrp +  8) * IN + k] * w;
            a2 += xsh[(rgrp + 16) * IN + k] * w;
            a3 += xsh[(rgrp + 24) * IN + k] * w;
        }
        zsh[(rgrp +  0) * 33 + h] = a0;
        zsh[(rgrp +  8) * 33 + h] = a1;
        zsh[(rgrp + 16) * 33 + h] = a2;
        zsh[(rgrp + 24) * 33 + h] = a3;
    }
    __syncthreads();

    // store z transposed: zT[h][b*32 + r], coalesced
#pragma unroll
    for (int j = 0; j < 4; ++j) {
        const int i = tid + 256 * j;          // 0..1023
        const int hh = i >> 5, rr = i & 31;
        ws[ZT + hh * NN + b * 32 + rr] = zsh[rr * 33 + hh];
    }
}

// ---------------------------------------------------------------- node B ---
__global__ __launch_bounds__(256) void kB_rest(const float* __restrict__ bases1,
                                               const float* __restrict__ coeff1,
                                               const float* __restrict__ bias1,
                                               const float* __restrict__ bases2,
                                               const float* __restrict__ coeff2,
                                               const float* __restrict__ loop_w2,
                                               const float* __restrict__ bias2,
                                               const float* __restrict__ ws,
                                               float* __restrict__ out) {
    __shared__ float w2sh[HID * OUTD];
    __shared__ float w2csh[HID * OUTD];
    __shared__ float h1own[128 * 33];      // 16.9 KB: own 128 rows (padded)
    __shared__ float red[256];
    __shared__ float s0sh[IN];
    __shared__ float agg1sh[HID];
    __shared__ float s1sh[HID];
    __shared__ float agg2sh[OUTD];
    const int tid = threadIdx.x, b = blockIdx.x;   // 16 blocks x 128 rows

    // stage w2 + combined basis2
    {
        const float c20 = coeff2[0], c21 = coeff2[1], c22 = coeff2[2], c23 = coeff2[3];
#pragma unroll
        for (int j = 0; j < 2; ++j) {
            const int i = tid + j * 256;
            w2sh[i]  = loop_w2[i];
            w2csh[i] = c20 * bases2[i]        + c21 * bases2[512 + i] +
                       c22 * bases2[1024 + i] + c23 * bases2[1536 + i];
        }
    }
    // s0 reduce (64 x 64 partials, tiny)
    {
        const int col = tid & 63, g = tid >> 6;
        float s = 0.f;
#pragma unroll
        for (int k = 0; k < 16; ++k)
            s += ws[S0P + (g * 16 + k) * 64 + col];
        red[tid] = s;
    }
    __syncthreads();
    if (tid < 64)
        s0sh[tid] = red[tid] + red[tid + 64] + red[tid + 128] + red[tid + 192];
    __syncthreads();

    // agg1[h] = bias1[h] + c1 * (s0 @ bases1[0])
    {
        const int h = tid & 31, seg = tid >> 5;
        float p = 0.f;
#pragma unroll
        for (int k = 0; k < 8; ++k)
            p += s0sh[seg * 8 + k] * bases1[(seg * 8 + k) * HID + h];
        red[tid] = p;
    }
    __syncthreads();
    if (tid < HID) {
        float t = 0.f;
#pragma unroll
        for (int g = 0; g < 8; ++g) t += red[g * 32 + tid];
        agg1sh[tid] = bias1[tid] + coeff1[0] * t;
    }
    __syncthreads();

    // s1[h] = sum_r relu(zT[h][r] + agg1[h]) — redundant, 256 KB/block,
    // staggered start per block (R5 lesson: avoid lockstep same-address reads).
    {
        const int h = tid >> 3, sub = tid & 7;
        const float a1h = agg1sh[h];
        const float4* z4 = (const float4*)(ws + ZT);
        float4 acc = make_float4(0.f, 0.f, 0.f, 0.f);
#pragma unroll 8
        for (int j = 0; j < 64; ++j) {
            const int jj = (j + b * 4) & 63;
            const float4 v = z4[h * (NN / 4) + 8 * jj + sub];
            acc.x += fmaxf(v.x + a1h, 0.f);
            acc.y += fmaxf(v.y + a1h, 0.f);
            acc.z += fmaxf(v.z + a1h, 0.f);
            acc.w += fmaxf(v.w + a1h, 0.f);
        }
        red[tid] = acc.x + acc.y + acc.z + acc.w;
    }
    __syncthreads();
    if (tid < HID) {
        float t = 0.f;
#pragma unroll
        for (int k = 0; k < 8; ++k) t += red[tid * 8 + k];
        s1sh[tid] = t;
    }
    __syncthreads();
    if (tid < OUTD) {
        float s = 0.f;
#pragma unroll
        for (int h = 0; h < HID; ++h) s += s1sh[h] * w2csh[h * OUTD + tid];
        agg2sh[tid] = bias2[tid] + s;
    }
    // own h1 tile: 128 rows x 32 h (16/thread), coalesced reads from zT
#pragma unroll
    for (int j = 0; j < 16; ++j) {
        const int i = tid + 256 * j;           // 0..4095
        const int hh = i >> 7, rr = i & 127;
        h1own[rr * 33 + hh] = fmaxf(ws[ZT + hh * NN + b * 128 + rr] + agg1sh[hh], 0.f);
    }
    __syncthreads();

    // out: own 128 rows x 16 cols (8/thread), coalesced
#pragma unroll
    for (int j = 0; j < 8; ++j) {
        const int idx = tid + j * 256;         // 0..2047
        const int row = idx >> 4, o = idx & 15;
        float acc = agg2sh[o];
#pragma unroll
        for (int h = 0; h < HID; ++h)
            acc += h1own[row * 33 + h] * w2sh[h * OUTD + o];
        out[b * 2048 + idx] = acc;
    }
}

extern "C" void kernel_launch(void* const* d_in, const int* in_sizes, int n_in,
                              void* d_out, int out_size, void* d_ws, size_t ws_size,
                              hipStream_t stream) {
    const float* x       = (const float*)d_in[0];
    // d_in[1] = adj_matrix: mathematically unused (complete graph w/ self-loops)
    const float* bases1  = (const float*)d_in[2];
    const float* coeff1  = (const float*)d_in[3];
    const float* loop_w1 = (const float*)d_in[4];
    const float* bias1   = (const float*)d_in[5];
    const float* bases2  = (const float*)d_in[6];
    const float* coeff2  = (const float*)d_in[7];
    const float* loop_w2 = (const float*)d_in[8];
    const float* bias2   = (const float*)d_in[9];
    float* out = (float*)d_out;
    float* ws  = (float*)d_ws;

    kA_z_s0<<<64, 256, 0, stream>>>(x, loop_w1, ws);
    kB_rest<<<16, 256, 0, stream>>>(bases1, coeff1, bias1,
                                    bases2, coeff2, loop_w2, bias2, ws, out);
}

// Round 9
// 89.327 us; speedup vs baseline: 1.0827x; 1.0827x over previous
//
#include <hip/hip_runtime.h>

#define NN   2048
#define IN   64
#define HID  32
#define OUTD 16

// FINAL (reverted to R3 — best measured, 89.3 us):
// Dataflow: s0=colsum(x) -> agg1 -> h1=relu(x@W1+agg1) -> s1=colsum(h1)
//           -> agg2 -> out = h1@W2 + agg2
// Two global reductions => 3 kernels (grid.sync measured slower, R1; spin
// barriers measured slower, R4; 2-node redundant variants tied or slower,
// R5-R7). Timed window is dominated by harness resets (~60 us incl. the
// 43 us 256 MB ws-poison fill) + ~3 dispatch overheads; device work ~8 us.
//
// ws layout (floats) — every slot is write-before-read (0xAA poison harmless):
//   [S0P, S0P+64*64)   : K1 per-block partial colsums of x   (64 blocks x 64)
//   [H1O, H1O+2048*32) : h1, row-major                       (written by K2)
//   [S1P, S1P+64*32)   : K2 per-block partial colsums of h1  (64 blocks x 32)
#define S0P 0
#define H1O 4096
#define S1P (4096 + NN * HID)

// ---------------------------------------------------------------- K1 -------
__global__ __launch_bounds__(256) void k1_colsum_x(const float* __restrict__ x,
                                                   float* __restrict__ ws) {
    __shared__ float red[256];
    const int tid = threadIdx.x, b = blockIdx.x;   // 64 blocks x 32 rows
    const int col = tid & 63, grp = tid >> 6;      // 4 groups x 8 rows
    const float* xb = x + b * 32 * IN;
    float s = 0.f;
#pragma unroll
    for (int r = 0; r < 8; ++r)                    // 8 independent coalesced loads
        s += xb[(grp * 8 + r) * IN + col];
    red[tid] = s;
    __syncthreads();
    if (tid < 64)
        ws[S0P + b * 64 + tid] = red[tid] + red[tid + 64] + red[tid + 128] + red[tid + 192];
}

// ---------------------------------------------------------------- K2 -------
__global__ __launch_bounds__(256) void k2_layer1(const float* __restrict__ x,
                                                 const float* __restrict__ bases1,
                                                 const float* __restrict__ coeff1,
                                                 const float* __restrict__ loop_w1,
                                                 const float* __restrict__ bias1,
                                                 float* __restrict__ ws) {
    __shared__ float w1sh[IN * HID];   // 8 KB
    __shared__ float xsh[32 * IN];     // 8 KB
    __shared__ float s0sh[IN];
    __shared__ float agg1sh[HID];
    __shared__ float red[256];
    const int tid = threadIdx.x, b = blockIdx.x;   // 64 blocks x 32 rows

    // stage own x tile + w1 (float4, 2/thread each, all independent)
    const float4* x4  = (const float4*)(x + b * 32 * IN);
    const float4* w14 = (const float4*)loop_w1;
    float4 xa = x4[tid], xb4 = x4[tid + 256];
    float4 wa = w14[tid], wb = w14[tid + 256];

    // reduce s0 partials (64 x 64) — 16 independent L2 loads per thread
    {
        const int col = tid & 63, g = tid >> 6;    // g sums blocks 16g..16g+15
        float a0 = 0.f, a1 = 0.f, a2 = 0.f, a3 = 0.f;
#pragma unroll
        for (int k = 0; k < 4; ++k) {
            a0 += ws[S0P + (g * 16 + k     ) * 64 + col];
            a1 += ws[S0P + (g * 16 + 4 + k ) * 64 + col];
            a2 += ws[S0P + (g * 16 + 8 + k ) * 64 + col];
            a3 += ws[S0P + (g * 16 + 12 + k) * 64 + col];
        }
        ((float4*)xsh)[tid] = xa; ((float4*)xsh)[tid + 256] = xb4;
        ((float4*)w1sh)[tid] = wa; ((float4*)w1sh)[tid + 256] = wb;
        red[tid] = a0 + a1 + a2 + a3;
    }
    __syncthreads();
    if (tid < 64)
        s0sh[tid] = red[tid] + red[tid + 64] + red[tid + 128] + red[tid + 192];
    __syncthreads();

    // agg1[h] = bias1[h] + c1 * sum_k s0[k]*bases1[k*HID+h]
    {
        const int h = tid & 31, seg = tid >> 5;
        float p = 0.f;
#pragma unroll
        for (int k = 0; k < 8; ++k)
            p += s0sh[seg * 8 + k] * bases1[(seg * 8 + k) * HID + h];
        red[tid] = p;
        __syncthreads();
        if (tid < HID) {
            float t = 0.f;
#pragma unroll
            for (int g = 0; g < 8; ++g) t += red[g * 32 + tid];
            agg1sh[tid] = bias1[tid] + coeff1[0] * t;
        }
    }
    __syncthreads();

    // h1 for 32 rows: thread = (h = tid&31, rgrp = tid>>5), rows rgrp + {0,8,16,24}
    {
        const int h = tid & 31, rgrp = tid >> 5;
        const float agg1v = agg1sh[h];
        float a0 = agg1v, a1 = agg1v, a2 = agg1v, a3 = agg1v;
#pragma unroll
        for (int k = 0; k < IN; ++k) {
            const float w = w1sh[k * HID + h];     // broadcast within wave
            a0 += xsh[(rgrp +  0) * IN + k] * w;
            a1 += xsh[(rgrp +  8) * IN + k] * w;
            a2 += xsh[(rgrp + 16) * IN + k] * w;
            a3 += xsh[(rgrp + 24) * IN + k] * w;
        }
        a0 = fmaxf(a0, 0.f); a1 = fmaxf(a1, 0.f);
        a2 = fmaxf(a2, 0.f); a3 = fmaxf(a3, 0.f);
        float* h1b = ws + H1O + b * 32 * HID;
        h1b[(rgrp +  0) * HID + h] = a0;
        h1b[(rgrp +  8) * HID + h] = a1;
        h1b[(rgrp + 16) * HID + h] = a2;
        h1b[(rgrp + 24) * HID + h] = a3;
        red[tid] = a0 + a1 + a2 + a3;              // partial s1
    }
    __syncthreads();
    if (tid < HID) {
        float t = 0.f;
#pragma unroll
        for (int g = 0; g < 8; ++g) t += red[g * 32 + tid];
        ws[S1P + b * HID + tid] = t;
    }
}

// ---------------------------------------------------------------- K3 -------
__global__ __launch_bounds__(256) void k3_layer2(const float* __restrict__ bases2,
                                                 const float* __restrict__ coeff2,
                                                 const float* __restrict__ loop_w2,
                                                 const float* __restrict__ bias2,
                                                 const float* __restrict__ ws,
                                                 float* __restrict__ out) {
    __shared__ float w2sh[HID * OUTD];     // loop_w2
    __shared__ float w2csh[HID * OUTD];    // sum_r coeff2[0,r]*bases2[r]
    __shared__ float h1sh[16 * (HID + 1)]; // own 16 rows, +1 pad
    __shared__ float s1sh[HID];
    __shared__ float agg2sh[OUTD];
    __shared__ float red[256];
    const int tid = threadIdx.x, b = blockIdx.x;   // 128 blocks x 16 rows

    // stage weights + combined basis (2 elements/thread)
    {
        const float c20 = coeff2[0], c21 = coeff2[1], c22 = coeff2[2], c23 = coeff2[3];
#pragma unroll
        for (int j = 0; j < 2; ++j) {
            const int i = tid + j * 256;
            w2sh[i]  = loop_w2[i];
            w2csh[i] = c20 * bases2[i]        + c21 * bases2[512 + i] +
                       c22 * bases2[1024 + i] + c23 * bases2[1536 + i];
        }
    }
    // own h1 tile: 512 floats, coalesced read, padded LDS write
    for (int j = 0; j < 2; ++j) {
        const int i = tid + j * 256;
        h1sh[(i >> 5) * (HID + 1) + (i & 31)] = ws[H1O + b * 16 * HID + i];
    }
    // reduce s1 partials (64 x 32): thread (h=tid&31, g=tid>>5) sums 8 blocks
    {
        const int h = tid & 31, g = tid >> 5;
        float a0 = 0.f, a1 = 0.f;
#pragma unroll
        for (int k = 0; k < 4; ++k) {
            a0 += ws[S1P + (g * 8 + k    ) * HID + h];
            a1 += ws[S1P + (g * 8 + 4 + k) * HID + h];
        }
        red[tid] = a0 + a1;
    }
    __syncthreads();
    if (tid < HID) {
        float t = 0.f;
#pragma unroll
        for (int g = 0; g < 8; ++g) t += red[g * 32 + tid];
        s1sh[tid] = t;
    }
    __syncthreads();
    if (tid < OUTD) {
        float s = 0.f;
#pragma unroll
        for (int h = 0; h < HID; ++h) s += s1sh[h] * w2csh[h * OUTD + tid];
        agg2sh[tid] = bias2[tid] + s;
    }
    __syncthreads();

    // out: 16 rows x 16 cols = 256 -> 1/thread, coalesced store
    {
        const int row = tid >> 4, o = tid & 15;
        float acc = agg2sh[o];
#pragma unroll
        for (int h = 0; h < HID; ++h)
            acc += h1sh[row * (HID + 1) + h] * w2sh[h * OUTD + o];
        out[b * 256 + tid] = acc;
    }
}

extern "C" void kernel_launch(void* const* d_in, const int* in_sizes, int n_in,
                              void* d_out, int out_size, void* d_ws, size_t ws_size,
                              hipStream_t stream) {
    const float* x       = (const float*)d_in[0];
    // d_in[1] = adj_matrix: mathematically unused (complete graph w/ self-loops)
    const float* bases1  = (const float*)d_in[2];
    const float* coeff1  = (const float*)d_in[3];
    const float* loop_w1 = (const float*)d_in[4];
    const float* bias1   = (const float*)d_in[5];
    const float* bases2  = (const float*)d_in[6];
    const float* coeff2  = (const float*)d_in[7];
    const float* loop_w2 = (const float*)d_in[8];
    const float* bias2   = (const float*)d_in[9];
    float* out = (float*)d_out;
    float* ws  = (float*)d_ws;

    k1_colsum_x<<<64, 256, 0, stream>>>(x, ws);
    k2_layer1 <<<64, 256, 0, stream>>>(x, bases1, coeff1, loop_w1, bias1, ws);
    k3_layer2 <<<128, 256, 0, stream>>>(bases2, coeff2, loop_w2, bias2, ws, out);
}